// Round 1
// baseline (14.897 us; speedup 1.0000x reference)
//
#include <hip/hip_runtime.h>
#include <hip/hip_bf16.h>

// Problem constants (from reference: B=4, D=128, N=512, fp32)
#define PB 4
#define PD 128
#define PN 512
#define NTILE 64              // n-columns per block (one wave-width)
#define OTILE 16              // output rows per block (4 waves x 4 rows)
#define NT (PN / NTILE)       // 8 n-tiles
#define OT (PD / OTILE)       // 8 o-tiles

// K1: per block (b, ot, nt): compute A = W1@x, C = W2@x + b for a
// [OTILE x NTILE] tile; store G = C - A and partial max over the tile's
// n-range of A into pmax[(b*D+o)*NT + nt].
__global__ __launch_bounds__(256) void gcn_k1(
    const float* __restrict__ x, const float* __restrict__ W1,
    const float* __restrict__ W2, const float* __restrict__ bias,
    float* __restrict__ G, float* __restrict__ pmax) {
  const int bid = blockIdx.x;
  const int nt = bid % NT;
  const int ot = (bid / NT) % OT;
  const int b = bid / (NT * OT);

  __shared__ float xs[PD][NTILE];       // 32 KB, [d][n]
  __shared__ float4 w1s[OTILE][PD / 4]; // 8 KB
  __shared__ float4 w2s[OTILE][PD / 4]; // 8 KB

  const int tid = threadIdx.x;

  // Stage x tile: 128 rows x 64 floats (16 float4 per row), coalesced.
  {
    const size_t xbase = (size_t)b * PD * PN + (size_t)nt * NTILE;
    for (int i = tid; i < PD * (NTILE / 4); i += 256) {
      const int d = i >> 4;          // / 16
      const int c = i & 15;          // % 16
      float4 v = *(const float4*)(x + xbase + (size_t)d * PN + c * 4);
      ((float4*)&xs[d][0])[c] = v;
    }
    // Stage W tiles: OTILE rows x 128 floats (32 float4 per row).
    for (int i = tid; i < OTILE * (PD / 4); i += 256) {
      const int r = i >> 5;          // / 32
      const int c = i & 31;          // % 32
      w1s[r][c] = *(const float4*)(W1 + (size_t)(ot * OTILE + r) * PD + c * 4);
      w2s[r][c] = *(const float4*)(W2 + (size_t)(ot * OTILE + r) * PD + c * 4);
    }
  }
  __syncthreads();

  const int lane = tid & 63;
  const int w = tid >> 6;        // wave 0..3
  const int o0 = w * 4;          // 4 rows per wave within the tile

  float accA[4] = {0.f, 0.f, 0.f, 0.f};
  float accC[4];
#pragma unroll
  for (int k = 0; k < 4; ++k) accC[k] = bias[ot * OTILE + o0 + k];

  for (int dc = 0; dc < PD / 4; ++dc) {
    const int d = dc * 4;
    const float xv0 = xs[d + 0][lane];
    const float xv1 = xs[d + 1][lane];
    const float xv2 = xs[d + 2][lane];
    const float xv3 = xs[d + 3][lane];
#pragma unroll
    for (int k = 0; k < 4; ++k) {
      const float4 w1v = w1s[o0 + k][dc];   // broadcast b128 read
      const float4 w2v = w2s[o0 + k][dc];
      accA[k] = fmaf(w1v.x, xv0, accA[k]);
      accA[k] = fmaf(w1v.y, xv1, accA[k]);
      accA[k] = fmaf(w1v.z, xv2, accA[k]);
      accA[k] = fmaf(w1v.w, xv3, accA[k]);
      accC[k] = fmaf(w2v.x, xv0, accC[k]);
      accC[k] = fmaf(w2v.y, xv1, accC[k]);
      accC[k] = fmaf(w2v.z, xv2, accC[k]);
      accC[k] = fmaf(w2v.w, xv3, accC[k]);
    }
  }

  // Wave-wide max over the 64 n-lanes for each of this wave's 4 rows.
  float m[4];
#pragma unroll
  for (int k = 0; k < 4; ++k) {
    float v = accA[k];
#pragma unroll
    for (int off = 32; off > 0; off >>= 1)
      v = fmaxf(v, __shfl_xor(v, off));
    m[k] = v;
  }

  // Write G = C - A (coalesced: 64 consecutive floats per row per wave).
  const size_t gbase =
      (size_t)b * PD * PN + (size_t)(ot * OTILE + o0) * PN + (size_t)nt * NTILE;
#pragma unroll
  for (int k = 0; k < 4; ++k)
    G[gbase + (size_t)k * PN + lane] = accC[k] - accA[k];

  if (lane == 0) {
#pragma unroll
    for (int k = 0; k < 4; ++k)
      pmax[(size_t)(b * PD + ot * OTILE + o0 + k) * NT + nt] = m[k];
  }
}

// K2: out = relu(G + maxA_row). 256 blocks x 256 threads; 2 rows per block,
// each thread one float4 of a row.
__global__ __launch_bounds__(256) void gcn_k2(
    const float* __restrict__ G, const float* __restrict__ pmax,
    float* __restrict__ out) {
  const int tid = threadIdx.x;
  const int row = blockIdx.x * 2 + (tid >> 7);   // (b*D + d), 0..511
  const int i = tid & 127;                        // float4 index within row

  float mv = pmax[(size_t)row * NT];
#pragma unroll
  for (int t = 1; t < NT; ++t)
    mv = fmaxf(mv, pmax[(size_t)row * NT + t]);

  const float4 g = ((const float4*)G)[(size_t)row * (PN / 4) + i];
  float4 o;
  o.x = fmaxf(g.x + mv, 0.f);
  o.y = fmaxf(g.y + mv, 0.f);
  o.z = fmaxf(g.z + mv, 0.f);
  o.w = fmaxf(g.w + mv, 0.f);
  ((float4*)out)[(size_t)row * (PN / 4) + i] = o;
}

extern "C" void kernel_launch(void* const* d_in, const int* in_sizes, int n_in,
                              void* d_out, int out_size, void* d_ws, size_t ws_size,
                              hipStream_t stream) {
  const float* x = (const float*)d_in[0];
  const float* W1 = (const float*)d_in[1];
  const float* W2 = (const float*)d_in[2];
  const float* bias = (const float*)d_in[3];
  float* out = (float*)d_out;

  float* G = (float*)d_ws;                                   // B*D*N floats = 1 MB
  float* pmax = (float*)((char*)d_ws + (size_t)PB * PD * PN * sizeof(float)); // 16 KB

  gcn_k1<<<dim3(PB * OT * NT), dim3(256), 0, stream>>>(x, W1, W2, bias, G, pmax);
  gcn_k2<<<dim3(PB * PD / 2), dim3(256), 0, stream>>>(G, pmax, out);
}